// Round 1
// baseline (202.750 us; speedup 1.0000x reference)
//
#include <hip/hip_runtime.h>

// Problem constants (from reference): S=2048, B=16, H=1024
#define SEQ 2048
#define BATCH 16
#define HID 1024

// ---------------------------------------------------------------------------
// Kernel 1: energy[b,h] = dot(state[b,:], W[h,:]) + bias[h]
// One 64-lane wave per output element. 4 waves (256 thr) per block.
// ---------------------------------------------------------------------------
__global__ __launch_bounds__(256) void energy_kernel(
    const float* __restrict__ state,   // [BATCH, HID] (= last_decoder_state[0,0])
    const float* __restrict__ W,       // [HID, HID]
    const float* __restrict__ bias,    // [HID]
    float* __restrict__ energy)        // [BATCH, HID]
{
    const int wave = threadIdx.x >> 6;
    const int lane = threadIdx.x & 63;
    const int o = blockIdx.x * 4 + wave;        // o in [0, BATCH*HID)
    const int b = o >> 10;                       // / HID
    const int h = o & (HID - 1);

    const float4* __restrict__ wrow = reinterpret_cast<const float4*>(W + (size_t)h * HID);
    const float4* __restrict__ srow = reinterpret_cast<const float4*>(state + (size_t)b * HID);

    float sum = 0.0f;
#pragma unroll
    for (int it = 0; it < HID / 4 / 64; ++it) {   // 1024/4 = 256 float4 -> 4 iters
        const int idx = it * 64 + lane;
        const float4 w4 = wrow[idx];
        const float4 s4 = srow[idx];
        sum = fmaf(w4.x, s4.x, sum);
        sum = fmaf(w4.y, s4.y, sum);
        sum = fmaf(w4.z, s4.z, sum);
        sum = fmaf(w4.w, s4.w, sum);
    }
#pragma unroll
    for (int off = 32; off > 0; off >>= 1) sum += __shfl_down(sum, off);
    if (lane == 0) energy[o] = sum + bias[h];
}

// ---------------------------------------------------------------------------
// Kernel 2: scores[s,b] = dot(enc[s,b,:], energy[b,:])
// One wave per (s,b) row; enc row is contiguous 4 KB -> float4 coalesced.
// ---------------------------------------------------------------------------
__global__ __launch_bounds__(256) void scores_kernel(
    const float* __restrict__ enc,     // [SEQ, BATCH, HID]
    const float* __restrict__ energy,  // [BATCH, HID]
    float* __restrict__ scores)        // [SEQ, BATCH] flat s*BATCH+b
{
    const int wave = threadIdx.x >> 6;
    const int lane = threadIdx.x & 63;
    const int o = blockIdx.x * 4 + wave;        // o = s*BATCH + b
    const int b = o & (BATCH - 1);

    const float4* __restrict__ erow = reinterpret_cast<const float4*>(enc + (size_t)o * HID);
    const float4* __restrict__ grow = reinterpret_cast<const float4*>(energy + (size_t)b * HID);

    float sum = 0.0f;
#pragma unroll
    for (int it = 0; it < HID / 4 / 64; ++it) {   // 4 iters
        const int idx = it * 64 + lane;
        const float4 e4 = erow[idx];
        const float4 g4 = grow[idx];
        sum = fmaf(e4.x, g4.x, sum);
        sum = fmaf(e4.y, g4.y, sum);
        sum = fmaf(e4.z, g4.z, sum);
        sum = fmaf(e4.w, g4.w, sum);
    }
#pragma unroll
    for (int off = 32; off > 0; off >>= 1) sum += __shfl_down(sum, off);
    if (lane == 0) scores[o] = sum;
}

// ---------------------------------------------------------------------------
// Kernel 3: softmax over s (axis 0) per column b. One block per b.
// 256 threads x 8 elements each = 2048.
// ---------------------------------------------------------------------------
__global__ __launch_bounds__(256) void softmax_kernel(
    const float* __restrict__ scores,  // [SEQ, BATCH]
    float* __restrict__ out)           // [SEQ, BATCH] (== [1,1,S,B] flat)
{
    const int b = blockIdx.x;
    const int t = threadIdx.x;

    float vals[SEQ / 256];
    float m = -INFINITY;
#pragma unroll
    for (int i = 0; i < SEQ / 256; ++i) {
        vals[i] = scores[(size_t)(t + i * 256) * BATCH + b];
        m = fmaxf(m, vals[i]);
    }

    __shared__ float redm[4];
#pragma unroll
    for (int off = 32; off > 0; off >>= 1) m = fmaxf(m, __shfl_xor(m, off));
    if ((t & 63) == 0) redm[t >> 6] = m;
    __syncthreads();
    m = fmaxf(fmaxf(redm[0], redm[1]), fmaxf(redm[2], redm[3]));

    float lsum = 0.0f;
#pragma unroll
    for (int i = 0; i < SEQ / 256; ++i) {
        vals[i] = expf(vals[i] - m);
        lsum += vals[i];
    }

    __shared__ float reds[4];
#pragma unroll
    for (int off = 32; off > 0; off >>= 1) lsum += __shfl_xor(lsum, off);
    if ((t & 63) == 0) reds[t >> 6] = lsum;
    __syncthreads();
    const float inv = 1.0f / (reds[0] + reds[1] + reds[2] + reds[3]);

#pragma unroll
    for (int i = 0; i < SEQ / 256; ++i)
        out[(size_t)(t + i * 256) * BATCH + b] = vals[i] * inv;
}

// ---------------------------------------------------------------------------
extern "C" void kernel_launch(void* const* d_in, const int* in_sizes, int n_in,
                              void* d_out, int out_size, void* d_ws, size_t ws_size,
                              hipStream_t stream) {
    const float* enc   = (const float*)d_in[0];   // [S,B,H]
    const float* lds   = (const float*)d_in[1];   // [2,1,B,H]; state = [0,0] at offset 0
    const float* W     = (const float*)d_in[2];   // [H,H]
    const float* bias  = (const float*)d_in[3];   // [H]
    float* out = (float*)d_out;                   // [1,1,S,B] = S*B floats

    float* energy = (float*)d_ws;                 // BATCH*HID floats = 64 KB
    float* scores = energy + BATCH * HID;         // SEQ*BATCH floats = 128 KB

    energy_kernel<<<BATCH * HID / 4, 256, 0, stream>>>(lds, W, bias, energy);
    scores_kernel<<<SEQ * BATCH / 4, 256, 0, stream>>>(enc, energy, scores);
    softmax_kernel<<<BATCH, 256, 0, stream>>>(scores, out);
}

// Round 2
// 199.938 us; speedup vs baseline: 1.0141x; 1.0141x over previous
//
#include <hip/hip_runtime.h>

// Problem constants (from reference): S=2048, B=16, H=1024
#define SEQ 2048
#define BATCH 16
#define HID 1024

// ---------------------------------------------------------------------------
// Kernel 1: energy[b,h] = dot(state[b,:], W[h,:]) + bias[h]
// One 64-lane wave per output element. 4 waves (256 thr) per block.
// ---------------------------------------------------------------------------
__global__ __launch_bounds__(256) void energy_kernel(
    const float* __restrict__ state,   // [BATCH, HID] (= last_decoder_state[0,0])
    const float* __restrict__ W,       // [HID, HID]
    const float* __restrict__ bias,    // [HID]
    float* __restrict__ energy)        // [BATCH, HID]
{
    const int wave = threadIdx.x >> 6;
    const int lane = threadIdx.x & 63;
    const int o = blockIdx.x * 4 + wave;        // o in [0, BATCH*HID)
    const int b = o >> 10;                       // / HID
    const int h = o & (HID - 1);

    const float4* __restrict__ wrow = reinterpret_cast<const float4*>(W + (size_t)h * HID);
    const float4* __restrict__ srow = reinterpret_cast<const float4*>(state + (size_t)b * HID);

    float sum = 0.0f;
#pragma unroll
    for (int it = 0; it < HID / 4 / 64; ++it) {   // 4 iters
        const int idx = it * 64 + lane;
        const float4 w4 = wrow[idx];
        const float4 s4 = srow[idx];
        sum = fmaf(w4.x, s4.x, sum);
        sum = fmaf(w4.y, s4.y, sum);
        sum = fmaf(w4.z, s4.z, sum);
        sum = fmaf(w4.w, s4.w, sum);
    }
#pragma unroll
    for (int off = 32; off > 0; off >>= 1) sum += __shfl_down(sum, off);
    if (lane == 0) energy[o] = sum + bias[h];
}

// ---------------------------------------------------------------------------
// Kernel 2: scoresT[b,s] = dot(enc[s,b,:], energy[b,:])
// One wave per 4 rows (same b): energy row loaded once into regs, 16
// independent enc float4 loads in flight. Contiguous float4 store into
// transposed scratch scoresT[B][S].
// ---------------------------------------------------------------------------
__global__ __launch_bounds__(256) void scores_kernel(
    const float* __restrict__ enc,     // [SEQ, BATCH, HID]
    const float* __restrict__ energy,  // [BATCH, HID]
    float* __restrict__ scoresT)       // [BATCH, SEQ]
{
    const int wave = threadIdx.x >> 6;
    const int lane = threadIdx.x & 63;
    const int w = blockIdx.x * 4 + wave;        // [0, 8192)
    const int b = w & (BATCH - 1);
    const int s0 = (w >> 4) * 4;                // 4 consecutive s per wave

    const float4* __restrict__ grow = reinterpret_cast<const float4*>(energy + (size_t)b * HID);
    float4 g[4];
#pragma unroll
    for (int it = 0; it < 4; ++it) g[it] = grow[it * 64 + lane];

    float sum[4] = {0.f, 0.f, 0.f, 0.f};
#pragma unroll
    for (int r = 0; r < 4; ++r) {
        const float4* __restrict__ erow =
            reinterpret_cast<const float4*>(enc + ((size_t)(s0 + r) * BATCH + b) * HID);
#pragma unroll
        for (int it = 0; it < 4; ++it) {
            const float4 e = erow[it * 64 + lane];
            sum[r] = fmaf(e.x, g[it].x, sum[r]);
            sum[r] = fmaf(e.y, g[it].y, sum[r]);
            sum[r] = fmaf(e.z, g[it].z, sum[r]);
            sum[r] = fmaf(e.w, g[it].w, sum[r]);
        }
    }
#pragma unroll
    for (int r = 0; r < 4; ++r) {
#pragma unroll
        for (int off = 32; off > 0; off >>= 1) sum[r] += __shfl_down(sum[r], off);
    }
    if (lane == 0) {
        float4 v = make_float4(sum[0], sum[1], sum[2], sum[3]);
        *reinterpret_cast<float4*>(scoresT + (size_t)b * SEQ + s0) = v;
    }
}

// ---------------------------------------------------------------------------
// Kernel 3: softmax over s per column b. One block per b; coalesced float4
// reads from scoresT; strided (layout-mandated) writes to out[S,B].
// ---------------------------------------------------------------------------
__global__ __launch_bounds__(256) void softmax_kernel(
    const float* __restrict__ scoresT, // [BATCH, SEQ]
    float* __restrict__ out)           // [SEQ, BATCH] (== [1,1,S,B] flat)
{
    const int b = blockIdx.x;
    const int t = threadIdx.x;
    const float4* __restrict__ row = reinterpret_cast<const float4*>(scoresT + (size_t)b * SEQ);

    float4 v0 = row[t];          // s = 4t .. 4t+3
    float4 v1 = row[t + 256];    // s = 4(t+256) ..

    float m = fmaxf(fmaxf(fmaxf(v0.x, v0.y), fmaxf(v0.z, v0.w)),
                    fmaxf(fmaxf(v1.x, v1.y), fmaxf(v1.z, v1.w)));

    __shared__ float redm[4];
#pragma unroll
    for (int off = 32; off > 0; off >>= 1) m = fmaxf(m, __shfl_xor(m, off));
    if ((t & 63) == 0) redm[t >> 6] = m;
    __syncthreads();
    m = fmaxf(fmaxf(redm[0], redm[1]), fmaxf(redm[2], redm[3]));

    v0.x = expf(v0.x - m); v0.y = expf(v0.y - m);
    v0.z = expf(v0.z - m); v0.w = expf(v0.w - m);
    v1.x = expf(v1.x - m); v1.y = expf(v1.y - m);
    v1.z = expf(v1.z - m); v1.w = expf(v1.w - m);

    float lsum = (v0.x + v0.y + v0.z + v0.w) + (v1.x + v1.y + v1.z + v1.w);

    __shared__ float reds[4];
#pragma unroll
    for (int off = 32; off > 0; off >>= 1) lsum += __shfl_xor(lsum, off);
    if ((t & 63) == 0) reds[t >> 6] = lsum;
    __syncthreads();
    const float inv = 1.0f / (reds[0] + reds[1] + reds[2] + reds[3]);

    const int s0 = t * 4;
    out[(size_t)(s0 + 0) * BATCH + b] = v0.x * inv;
    out[(size_t)(s0 + 1) * BATCH + b] = v0.y * inv;
    out[(size_t)(s0 + 2) * BATCH + b] = v0.z * inv;
    out[(size_t)(s0 + 3) * BATCH + b] = v0.w * inv;
    const int s1 = (t + 256) * 4;
    out[(size_t)(s1 + 0) * BATCH + b] = v1.x * inv;
    out[(size_t)(s1 + 1) * BATCH + b] = v1.y * inv;
    out[(size_t)(s1 + 2) * BATCH + b] = v1.z * inv;
    out[(size_t)(s1 + 3) * BATCH + b] = v1.w * inv;
}

// ---------------------------------------------------------------------------
extern "C" void kernel_launch(void* const* d_in, const int* in_sizes, int n_in,
                              void* d_out, int out_size, void* d_ws, size_t ws_size,
                              hipStream_t stream) {
    const float* enc   = (const float*)d_in[0];   // [S,B,H]
    const float* lds   = (const float*)d_in[1];   // [2,1,B,H]; state = [0,0] at offset 0
    const float* W     = (const float*)d_in[2];   // [H,H]
    const float* bias  = (const float*)d_in[3];   // [H]
    float* out = (float*)d_out;                   // [1,1,S,B] = S*B floats

    float* energy  = (float*)d_ws;                // BATCH*HID floats = 64 KB
    float* scoresT = energy + BATCH * HID;        // BATCH*SEQ floats = 128 KB

    energy_kernel<<<BATCH * HID / 4, 256, 0, stream>>>(lds, W, bias, energy);
    scores_kernel<<<SEQ * BATCH / 4 / 4, 256, 0, stream>>>(enc, energy, scoresT);
    softmax_kernel<<<BATCH, 256, 0, stream>>>(scoresT, out);
}